// Round 2
// 484.068 us; speedup vs baseline: 1.0076x; 1.0076x over previous
//
#include <hip/hip_runtime.h>

#define DD    64      // D
#define TWOD  128     // 2*D
#define RD    256     // RANK*D

typedef __attribute__((ext_vector_type(8))) short short8;   // 8 bf16 (MFMA A/B frag)
typedef __attribute__((ext_vector_type(4))) float float4v;  // MFMA C/D frag
typedef __attribute__((ext_vector_type(4))) unsigned uint4v;
typedef unsigned long long ull;

__device__ __forceinline__ unsigned short f2b(float f) {
    unsigned u = __builtin_bit_cast(unsigned, f);
    u += 0x7fffu + ((u >> 16) & 1u);
    return (unsigned short)(u >> 16);
}
__device__ __forceinline__ float b2f(unsigned short s) {
    unsigned u = ((unsigned)s) << 16;
    return __builtin_bit_cast(float, u);
}
// packed f32->bf16 RNE: one VALU op for two converts (identical rounding to f2b)
__device__ __forceinline__ unsigned cvt_pk_bf16(float lo, float hi) {
    unsigned r;
    asm("v_cvt_pk_bf16_f32 %0, %1, %2" : "=v"(r) : "v"(lo), "v"(hi));
    return r;
}
__device__ __forceinline__ float ftanh(float x) {
    float e = __expf(2.0f * x);
    return 1.0f - 2.0f / (e + 1.0f);
}
// Single-wave workgroup: DS ops execute in order per wave, so lgkmcnt(0) +
// a compiler memory fence replaces __syncthreads() (no vmcnt(0) drain ->
// global prefetches stay in flight across stage boundaries).
__device__ __forceinline__ void lds_fence() {
    asm volatile("s_waitcnt lgkmcnt(0)" ::: "memory");
}

// ---------------------------------------------------------------------------
// Prep: bf16 weight layouts so MFMA B-frags are contiguous 16B reads.
//   wa [128][64]  = W1      (GEMM1: h  = x  @ W1^T)
//   wd [64][128]  = W1^T    (GEMM4: dx = da1@ W1)
//   wb [256][128] = W2      (GEMM2: u  = h  @ W2^T)
//   wc [128][256] = W2^T    (GEMM3: dh = da2@ W2)
// ---------------------------------------------------------------------------
__global__ void prep_weights(const float* __restrict__ W1, const float* __restrict__ W2,
                             unsigned short* __restrict__ wa, unsigned short* __restrict__ wd,
                             unsigned short* __restrict__ wb, unsigned short* __restrict__ wc) {
    int t = blockIdx.x * blockDim.x + threadIdx.x;
    if (t < 8192) {
        wa[t] = f2b(W1[t]);
        int c = t >> 7, r = t & 127;
        wd[t] = f2b(W1[r * 64 + c]);
    }
    if (t < 32768) {
        wb[t] = f2b(W2[t]);
        int c = t >> 8, k = t & 255;
        wc[t] = f2b(W2[k * 128 + c]);
    }
}

// ---------------------------------------------------------------------------
// One wave per 16-row tile. LDS 13056 B -> 12 blocks/CU (was 17408 -> 9).
//   * h_s/d_s time-aliased in one buffer hd_s (live ranges disjoint; each
//     dying alias is fully consumed into registers wave-wide before the
//     lgkmcnt(0) drain that precedes the first overwriting store).
//   * v kept in LDS (v_s) for GEMM2's cross-lane read (lane needs another
//     lane's column at its OWN row -- shuffle cannot express that), but the
//     mid-pass uses a 16-register copy vreg (lane's own column).
// ---------------------------------------------------------------------------
__global__ __launch_bounds__(64, 3) void geognn_kernel(
    const float* __restrict__ inp, const float* __restrict__ b1, const float* __restrict__ b2,
    const unsigned short* __restrict__ wa, const unsigned short* __restrict__ wd,
    const unsigned short* __restrict__ wb, const unsigned short* __restrict__ wc,
    float* __restrict__ out) {

    // phase A (GEMM1->GEMM2, GEMM3->GEMM4): h layout, stride 136 (4352 B used)
    // phase B (GEMM2->mid->GEMM3):          d layout, stride 264 (8448 B used)
    __shared__ __align__(16) unsigned short hd_s[16 * 264];   // 8448 B
    __shared__ float v_s[16][68];                              // 4352 B
    __shared__ float4v y_s[16];                                // 256 B

    const int  l   = threadIdx.x;
    const int  l15 = l & 15;
    const int  q   = l >> 4;
    const long row0 = (long)blockIdx.x * 16;

    // ---- V tile: LDS copy (cross-lane use in GEMM2) + register copy (mid-pass) ----
    float vreg[16];
#pragma unroll
    for (int r = 0; r < 16; ++r) {
        float vv = inp[(row0 + r) * TWOD + DD + l];
        v_s[r][l] = vv;
        vreg[r]   = vv;
    }

    // ---- x A-frags from global: A[m=l15][k=kb*32+q*8+j] ----
    short8 ax[2];
#pragma unroll
    for (int kb = 0; kb < 2; ++kb) {
        const float4v* p = (const float4v*)(inp + (row0 + l15) * TWOD + kb * 32 + q * 8);
        float4v f0 = p[0], f1 = p[1];
        uint4v pk = { cvt_pk_bf16(f0.x, f0.y), cvt_pk_bf16(f0.z, f0.w),
                      cvt_pk_bf16(f1.x, f1.y), cvt_pk_bf16(f1.z, f1.w) };
        ax[kb] = __builtin_bit_cast(short8, pk);
    }

    // biases (lane's C-columns: n = nb*16 + l15)
    float b1v[8];
#pragma unroll
    for (int nb = 0; nb < 8; ++nb) b1v[nb] = b1[nb * 16 + l15];
    float b2v[16];
#pragma unroll
    for (int nb = 0; nb < 16; ++nb) b2v[nb] = b2[nb * 16 + l15];

    // ---- GEMM1: h = tanh(x @ W1^T + b1)  (16x64x128); all 16 B-frags preloaded ----
    short8 aw[16];
#pragma unroll
    for (int h = 0; h < 16; ++h)
        aw[h] = *(const short8*)(wa + ((h >> 1) * 16 + l15) * DD + (h & 1) * 32 + q * 8);

    unsigned g1p[16];   // packed bf16 (1-h^2), pairs over i: g1p[nb*2+(i>>1)]
#pragma unroll
    for (int nb = 0; nb < 8; ++nb) {
        float4v acc = {0.f, 0.f, 0.f, 0.f};
        acc = __builtin_amdgcn_mfma_f32_16x16x32_bf16(ax[0], aw[nb * 2 + 0], acc, 0, 0, 0);
        acc = __builtin_amdgcn_mfma_f32_16x16x32_bf16(ax[1], aw[nb * 2 + 1], acc, 0, 0, 0);
        int c = nb * 16 + l15;
#pragma unroll
        for (int i = 0; i < 4; i += 2) {
            float h0 = ftanh(acc[i]     + b1v[nb]);
            float h1 = ftanh(acc[i + 1] + b1v[nb]);
            hd_s[(q * 4 + i) * 136 + c]     = f2b(h0);
            hd_s[(q * 4 + i + 1) * 136 + c] = f2b(h1);
            g1p[nb * 2 + (i >> 1)] = cvt_pk_bf16(1.f - h0 * h0, 1.f - h1 * h1);
        }
    }

    // preload GEMM2 pair-0 B-frags BEFORE the fence (stays in flight across it)
    short8 bwA[8], bwB[8];
#pragma unroll
    for (int h = 0; h < 8; ++h)
        bwA[h] = *(const short8*)(wb + ((h >> 2) * 16 + l15) * TWOD + (h & 3) * 32 + q * 8);

    lds_fence();   // h writes, v_s visible wave-wide

    // ---- GEMM2: u = tanh(h @ W2^T + b2)  (16x128x256), fused y partials ----
    short8 ha[4];
#pragma unroll
    for (int kb = 0; kb < 4; ++kb)
        ha[kb] = *(const short8*)(&hd_s[l15 * 136 + kb * 32 + q * 8]);

    lds_fence();   // drain ha reads: h alias dies, d alias writes may begin

    float yp[4] = {0.f, 0.f, 0.f, 0.f};
#pragma unroll
    for (int p = 0; p < 8; ++p) {
        short8* cur = (p & 1) ? bwB : bwA;
        short8* nxt = (p & 1) ? bwA : bwB;
        if (p < 7) {
#pragma unroll
            for (int h = 0; h < 8; ++h)
                nxt[h] = *(const short8*)(wb + (((p + 1) * 2 + (h >> 2)) * 16 + l15) * TWOD
                                          + (h & 3) * 32 + q * 8);
        }
#pragma unroll
        for (int s = 0; s < 2; ++s) {
            const int nb = p * 2 + s;
            float4v acc = {0.f, 0.f, 0.f, 0.f};
#pragma unroll
            for (int kb = 0; kb < 4; ++kb)
                acc = __builtin_amdgcn_mfma_f32_16x16x32_bf16(ha[kb], cur[s * 4 + kb], acc, 0, 0, 0);
            const int n = nb * 16 + l15;
#pragma unroll
            for (int i = 0; i < 4; ++i) {
                const int r = q * 4 + i;
                float u = ftanh(acc[i] + b2v[nb]);
                hd_s[r * 264 + n] = f2b(u);
                yp[i] += v_s[r][n >> 2] * u;
            }
        }
    }

    // complete y (each j=l15&3 summed over the 4 lanes sharing it within the quad-row group)
#pragma unroll
    for (int i = 0; i < 4; ++i) {
        yp[i] += __shfl_xor(yp[i], 4, 64);
        yp[i] += __shfl_xor(yp[i], 8, 64);
    }
    if (l15 < 4) {
#pragma unroll
        for (int i = 0; i < 4; ++i)
            ((float*)&y_s[q * 4 + i])[l15] = yp[i];
    }

    // preload GEMM3 nb=0 B-frags before the fence
    short8 cwA[8], cwB[8];
#pragma unroll
    for (int kb = 0; kb < 8; ++kb)
        cwA[kb] = *(const short8*)(wc + l15 * RD + kb * 32 + q * 8);

    lds_fence();   // u (d alias), y_s visible

    // ---- fused mid-pass: per row, lane l owns cells n=4l..4l+3 of u ----
    //   dv_l = 2*sum_j y_j*u[4l+j]  -> out (coalesced)
    //   da2[4l+j] = 2*y_j*v_l*(1-u^2) -> write back in place (same lane, same addr)
#pragma unroll
    for (int r = 0; r < 16; ++r) {
        ull uu = *(const ull*)(&hd_s[r * 264 + 4 * l]);
        float4v y = y_s[r];
        float vv = vreg[r];
        float u0 = b2f((unsigned short)uu);
        float u1 = b2f((unsigned short)(uu >> 16));
        float u2 = b2f((unsigned short)(uu >> 32));
        float u3 = b2f((unsigned short)(uu >> 48));
        float dvv = y.x * u0 + y.y * u1 + y.z * u2 + y.w * u3;
        out[(row0 + r) * TWOD + DD + l] = -2.0f * dvv;
        float t0 = 2.0f * y.x * vv * (1.0f - u0 * u0);
        float t1 = 2.0f * y.y * vv * (1.0f - u1 * u1);
        float t2 = 2.0f * y.z * vv * (1.0f - u2 * u2);
        float t3 = 2.0f * y.w * vv * (1.0f - u3 * u3);
        unsigned w0 = cvt_pk_bf16(t0, t1);
        unsigned w1 = cvt_pk_bf16(t2, t3);
        ull w = (ull)w0 | ((ull)w1 << 32);
        *(ull*)(&hd_s[r * 264 + 4 * l]) = w;
    }

    lds_fence();   // da2 visible

    // ---- GEMM3: dh = da2 @ W2  (16x256x128); da1 = dh*(1-h^2) -> h alias ----
    short8 da[8];
#pragma unroll
    for (int kb = 0; kb < 8; ++kb)
        da[kb] = *(const short8*)(&hd_s[l15 * 264 + kb * 32 + q * 8]);

    lds_fence();   // drain da reads: d alias dies, h alias (da1) writes may begin

#pragma unroll
    for (int nb = 0; nb < 8; ++nb) {
        short8* cur = (nb & 1) ? cwB : cwA;
        short8* nxt = (nb & 1) ? cwA : cwB;
        if (nb < 7) {
#pragma unroll
            for (int kb = 0; kb < 8; ++kb)
                nxt[kb] = *(const short8*)(wc + ((nb + 1) * 16 + l15) * RD + kb * 32 + q * 8);
        }
        float4v acc = {0.f, 0.f, 0.f, 0.f};
#pragma unroll
        for (int kb = 0; kb < 8; ++kb)
            acc = __builtin_amdgcn_mfma_f32_16x16x32_bf16(da[kb], cur[kb], acc, 0, 0, 0);
        const int c = nb * 16 + l15;
#pragma unroll
        for (int i = 0; i < 4; ++i) {
            unsigned short gh = (i & 1) ? (unsigned short)(g1p[nb * 2 + (i >> 1)] >> 16)
                                        : (unsigned short)(g1p[nb * 2 + (i >> 1)]);
            hd_s[(q * 4 + i) * 136 + c] = f2b(acc[i] * b2f(gh));
        }
    }

    // preload all 16 GEMM4 B-frags before the fence
    short8 dw[16];
#pragma unroll
    for (int h = 0; h < 16; ++h)
        dw[h] = *(const short8*)(wd + ((h >> 2) * 16 + l15) * TWOD + (h & 3) * 32 + q * 8);

    lds_fence();   // da1 visible

    // ---- GEMM4: dx = da1 @ W1  (16x128x64) -> out[:, :64] ----
    short8 dfa[4];
#pragma unroll
    for (int kb = 0; kb < 4; ++kb)
        dfa[kb] = *(const short8*)(&hd_s[l15 * 136 + kb * 32 + q * 8]);
#pragma unroll
    for (int nb = 0; nb < 4; ++nb) {
        float4v acc = {0.f, 0.f, 0.f, 0.f};
#pragma unroll
        for (int kb = 0; kb < 4; ++kb)
            acc = __builtin_amdgcn_mfma_f32_16x16x32_bf16(dfa[kb], dw[nb * 4 + kb], acc, 0, 0, 0);
#pragma unroll
        for (int i = 0; i < 4; ++i)
            out[(row0 + q * 4 + i) * TWOD + nb * 16 + l15] = acc[i];
    }
}

extern "C" void kernel_launch(void* const* d_in, const int* in_sizes, int n_in,
                              void* d_out, int out_size, void* d_ws, size_t ws_size,
                              hipStream_t stream) {
    const float* inp = (const float*)d_in[1];
    const float* W1  = (const float*)d_in[2];
    const float* b1  = (const float*)d_in[3];
    const float* W2  = (const float*)d_in[4];
    const float* b2  = (const float*)d_in[5];

    unsigned short* wa = (unsigned short*)d_ws;
    unsigned short* wd = wa + 8192;
    unsigned short* wb = wd + 8192;
    unsigned short* wc = wb + 32768;

    prep_weights<<<128, 256, 0, stream>>>(W1, W2, wa, wd, wb, wc);

    const int rows = in_sizes[1] / TWOD;
    geognn_kernel<<<rows / 16, 64, 0, stream>>>(inp, b1, b2, wa, wd, wb, wc,
                                                (float*)d_out);
}

// Round 3
// 361.227 us; speedup vs baseline: 1.3503x; 1.3401x over previous
//
#include <hip/hip_runtime.h>

#define DD    64      // D
#define TWOD  128     // 2*D
#define RD    256     // RANK*D

typedef __attribute__((ext_vector_type(8))) short short8;   // 8 bf16 (MFMA A/B frag)
typedef __attribute__((ext_vector_type(4))) float float4v;  // MFMA C/D frag
typedef __attribute__((ext_vector_type(4))) unsigned uint4v;
typedef unsigned long long ull;

__device__ __forceinline__ unsigned short f2b(float f) {
    unsigned u = __builtin_bit_cast(unsigned, f);
    u += 0x7fffu + ((u >> 16) & 1u);
    return (unsigned short)(u >> 16);
}
__device__ __forceinline__ float b2f(unsigned short s) {
    unsigned u = ((unsigned)s) << 16;
    return __builtin_bit_cast(float, u);
}
// packed f32->bf16 RNE: one VALU op for two converts (identical rounding to f2b)
__device__ __forceinline__ unsigned cvt_pk_bf16(float lo, float hi) {
    unsigned r;
    asm("v_cvt_pk_bf16_f32 %0, %1, %2" : "=v"(r) : "v"(lo), "v"(hi));
    return r;
}
__device__ __forceinline__ float ftanh(float x) {
    float e = __expf(2.0f * x);
    return 1.0f - 2.0f / (e + 1.0f);
}
// Single-wave workgroup: DS ops execute in order per wave, so lgkmcnt(0) +
// a compiler memory fence replaces __syncthreads() (no vmcnt(0) drain ->
// global prefetches stay in flight across stage boundaries).
__device__ __forceinline__ void lds_fence() {
    asm volatile("s_waitcnt lgkmcnt(0)" ::: "memory");
}

// ---------------------------------------------------------------------------
// Prep: bf16 weight layouts so MFMA B-frags are contiguous 16B reads.
//   wa [128][64]  = W1      (GEMM1: h  = x  @ W1^T)
//   wd [64][128]  = W1^T    (GEMM4: dx = da1@ W1)
//   wb [256][128] = W2      (GEMM2: u  = h  @ W2^T)
//   wc [128][256] = W2^T    (GEMM3: dh = da2@ W2)
// ---------------------------------------------------------------------------
__global__ void prep_weights(const float* __restrict__ W1, const float* __restrict__ W2,
                             unsigned short* __restrict__ wa, unsigned short* __restrict__ wd,
                             unsigned short* __restrict__ wb, unsigned short* __restrict__ wc) {
    int t = blockIdx.x * blockDim.x + threadIdx.x;
    if (t < 8192) {
        wa[t] = f2b(W1[t]);
        int c = t >> 7, r = t & 127;
        wd[t] = f2b(W1[r * 64 + c]);
    }
    if (t < 32768) {
        wb[t] = f2b(W2[t]);
        int c = t >> 8, k = t & 255;
        wc[t] = f2b(W2[k * 128 + c]);
    }
}

// ---------------------------------------------------------------------------
// One wave per 32-row tile (two 16-row subtiles), PHASE-MAJOR: each weight
// fragment batch is loaded once and consumed by both subtiles, halving the
// per-row weight VMEM stream (the measured latency bottleneck: R2 showed
// occupancy +23% -> +0.4% perf; the wave's serialized weight-load latency
// is the critical path). LDS 26112 B -> 6 blocks/CU; launch_bounds(64,2)
// gives the register allocator room (cap 256) to keep prefetch buffers live.
// ---------------------------------------------------------------------------
__global__ __launch_bounds__(64, 2) void geognn_kernel(
    const float* __restrict__ inp, const float* __restrict__ b1, const float* __restrict__ b2,
    const unsigned short* __restrict__ wa, const unsigned short* __restrict__ wd,
    const unsigned short* __restrict__ wb, const unsigned short* __restrict__ wc,
    float* __restrict__ out) {

    // per subtile: phase A (GEMM1->2, 3->4) stride 136 (4352 B);
    //              phase B (GEMM2->mid->3)  stride 264 (8448 B). Time-aliased.
    __shared__ __align__(16) unsigned short hd_s[2][16 * 264];   // 16896 B
    __shared__ float v_s[2][16][68];                              // 8704 B
    __shared__ float4v y_s[2][16];                                // 512 B

    const int  l   = threadIdx.x;
    const int  l15 = l & 15;
    const int  q   = l >> 4;
    const long row0 = (long)blockIdx.x * 32;

    // ---- V tiles -> LDS (cross-lane use in GEMM2, own-lane use in mid-pass) ----
#pragma unroll
    for (int t = 0; t < 2; ++t)
#pragma unroll
        for (int r = 0; r < 16; ++r)
            v_s[t][r][l] = inp[(row0 + t * 16 + r) * TWOD + DD + l];

    // ---- x A-frags, both subtiles: A[m=l15][k=kb*32+q*8+j] ----
    short8 ax[2][2];
#pragma unroll
    for (int t = 0; t < 2; ++t)
#pragma unroll
        for (int kb = 0; kb < 2; ++kb) {
            const float4v* p = (const float4v*)(inp + (row0 + t * 16 + l15) * TWOD + kb * 32 + q * 8);
            float4v f0 = p[0], f1 = p[1];
            uint4v pk = { cvt_pk_bf16(f0.x, f0.y), cvt_pk_bf16(f0.z, f0.w),
                          cvt_pk_bf16(f1.x, f1.y), cvt_pk_bf16(f1.z, f1.w) };
            ax[t][kb] = __builtin_bit_cast(short8, pk);
        }

    // biases (lane's C-columns: n = nb*16 + l15)
    float b1v[8];
#pragma unroll
    for (int nb = 0; nb < 8; ++nb) b1v[nb] = b1[nb * 16 + l15];
    float b2v[16];
#pragma unroll
    for (int nb = 0; nb < 16; ++nb) b2v[nb] = b2[nb * 16 + l15];

    // ---- GEMM1: h = tanh(x @ W1^T + b1)  (32x64x128); 16 B-frags, used 2x ----
    short8 aw[16];
#pragma unroll
    for (int h = 0; h < 16; ++h)
        aw[h] = *(const short8*)(wa + ((h >> 1) * 16 + l15) * DD + (h & 1) * 32 + q * 8);

    unsigned g1p[2][16];   // packed bf16 (1-h^2), pairs over i
#pragma unroll
    for (int nb = 0; nb < 8; ++nb) {
        const int c = nb * 16 + l15;
#pragma unroll
        for (int t = 0; t < 2; ++t) {
            float4v acc = {0.f, 0.f, 0.f, 0.f};
            acc = __builtin_amdgcn_mfma_f32_16x16x32_bf16(ax[t][0], aw[nb * 2 + 0], acc, 0, 0, 0);
            acc = __builtin_amdgcn_mfma_f32_16x16x32_bf16(ax[t][1], aw[nb * 2 + 1], acc, 0, 0, 0);
#pragma unroll
            for (int i = 0; i < 4; i += 2) {
                float h0 = ftanh(acc[i]     + b1v[nb]);
                float h1 = ftanh(acc[i + 1] + b1v[nb]);
                hd_s[t][(q * 4 + i) * 136 + c]     = f2b(h0);
                hd_s[t][(q * 4 + i + 1) * 136 + c] = f2b(h1);
                g1p[t][nb * 2 + (i >> 1)] = cvt_pk_bf16(1.f - h0 * h0, 1.f - h1 * h1);
            }
        }
    }

    // preload GEMM2 pair-0 B-frags BEFORE the fence (stays in flight across it)
    short8 bwA[8], bwB[8];
#pragma unroll
    for (int h = 0; h < 8; ++h)
        bwA[h] = *(const short8*)(wb + ((h >> 2) * 16 + l15) * TWOD + (h & 3) * 32 + q * 8);

    lds_fence();   // h writes, v_s visible wave-wide

    // ---- GEMM2: u = tanh(h @ W2^T + b2)  (32x128x256), fused y partials ----
    short8 ha[2][4];
#pragma unroll
    for (int t = 0; t < 2; ++t)
#pragma unroll
        for (int kb = 0; kb < 4; ++kb)
            ha[t][kb] = *(const short8*)(&hd_s[t][l15 * 136 + kb * 32 + q * 8]);

    lds_fence();   // drain ha reads: h alias dies, d alias writes may begin

    float yp[2][4] = {{0.f, 0.f, 0.f, 0.f}, {0.f, 0.f, 0.f, 0.f}};
#pragma unroll
    for (int p = 0; p < 8; ++p) {
        short8* cur = (p & 1) ? bwB : bwA;
        short8* nxt = (p & 1) ? bwA : bwB;
        if (p < 7) {
#pragma unroll
            for (int h = 0; h < 8; ++h)
                nxt[h] = *(const short8*)(wb + (((p + 1) * 2 + (h >> 2)) * 16 + l15) * TWOD
                                          + (h & 3) * 32 + q * 8);
        }
#pragma unroll
        for (int s = 0; s < 2; ++s) {
            const int nb = p * 2 + s;
            const int n  = nb * 16 + l15;
#pragma unroll
            for (int t = 0; t < 2; ++t) {
                float4v acc = {0.f, 0.f, 0.f, 0.f};
#pragma unroll
                for (int kb = 0; kb < 4; ++kb)
                    acc = __builtin_amdgcn_mfma_f32_16x16x32_bf16(ha[t][kb], cur[s * 4 + kb], acc, 0, 0, 0);
#pragma unroll
                for (int i = 0; i < 4; ++i) {
                    const int r = q * 4 + i;
                    float u = ftanh(acc[i] + b2v[nb]);
                    hd_s[t][r * 264 + n] = f2b(u);
                    yp[t][i] += v_s[t][r][n >> 2] * u;
                }
            }
        }
    }

    // complete y (each j=l15&3 summed over the 4 lanes sharing it within the quad-row group)
#pragma unroll
    for (int t = 0; t < 2; ++t)
#pragma unroll
        for (int i = 0; i < 4; ++i) {
            yp[t][i] += __shfl_xor(yp[t][i], 4, 64);
            yp[t][i] += __shfl_xor(yp[t][i], 8, 64);
        }
    if (l15 < 4) {
#pragma unroll
        for (int t = 0; t < 2; ++t)
#pragma unroll
            for (int i = 0; i < 4; ++i)
                ((float*)&y_s[t][q * 4 + i])[l15] = yp[t][i];
    }

    // preload GEMM3 nb=0 B-frags before the fence
    short8 cwA[8], cwB[8];
#pragma unroll
    for (int kb = 0; kb < 8; ++kb)
        cwA[kb] = *(const short8*)(wc + l15 * RD + kb * 32 + q * 8);

    lds_fence();   // u (d alias), y_s visible

    // ---- fused mid-pass: per row, lane l owns cells n=4l..4l+3 of u ----
    //   dv_l = 2*sum_j y_j*u[4l+j]  -> out (coalesced)
    //   da2[4l+j] = 2*y_j*v_l*(1-u^2) -> write back in place (same lane, same addr)
#pragma unroll
    for (int t = 0; t < 2; ++t)
#pragma unroll
        for (int r = 0; r < 16; ++r) {
            ull uu = *(const ull*)(&hd_s[t][r * 264 + 4 * l]);
            float4v y = y_s[t][r];
            float vv = v_s[t][r][l];
            float u0 = b2f((unsigned short)uu);
            float u1 = b2f((unsigned short)(uu >> 16));
            float u2 = b2f((unsigned short)(uu >> 32));
            float u3 = b2f((unsigned short)(uu >> 48));
            float dvv = y.x * u0 + y.y * u1 + y.z * u2 + y.w * u3;
            out[(row0 + t * 16 + r) * TWOD + DD + l] = -2.0f * dvv;
            float t0 = 2.0f * y.x * vv * (1.0f - u0 * u0);
            float t1 = 2.0f * y.y * vv * (1.0f - u1 * u1);
            float t2 = 2.0f * y.z * vv * (1.0f - u2 * u2);
            float t3 = 2.0f * y.w * vv * (1.0f - u3 * u3);
            unsigned w0 = cvt_pk_bf16(t0, t1);
            unsigned w1 = cvt_pk_bf16(t2, t3);
            ull w = (ull)w0 | ((ull)w1 << 32);
            *(ull*)(&hd_s[t][r * 264 + 4 * l]) = w;
        }

    lds_fence();   // da2 visible

    // ---- GEMM3: dh = da2 @ W2  (32x256x128); da1 = dh*(1-h^2) -> h alias ----
    short8 da[2][8];
#pragma unroll
    for (int t = 0; t < 2; ++t)
#pragma unroll
        for (int kb = 0; kb < 8; ++kb)
            da[t][kb] = *(const short8*)(&hd_s[t][l15 * 264 + kb * 32 + q * 8]);

    lds_fence();   // drain da reads: d alias dies, h alias (da1) writes may begin

#pragma unroll
    for (int nb = 0; nb < 8; ++nb) {
        short8* cur = (nb & 1) ? cwB : cwA;
        short8* nxt = (nb & 1) ? cwA : cwB;
        if (nb < 7) {
#pragma unroll
            for (int kb = 0; kb < 8; ++kb)
                nxt[kb] = *(const short8*)(wc + ((nb + 1) * 16 + l15) * RD + kb * 32 + q * 8);
        }
        const int c = nb * 16 + l15;
#pragma unroll
        for (int t = 0; t < 2; ++t) {
            float4v acc = {0.f, 0.f, 0.f, 0.f};
#pragma unroll
            for (int kb = 0; kb < 8; ++kb)
                acc = __builtin_amdgcn_mfma_f32_16x16x32_bf16(da[t][kb], cur[kb], acc, 0, 0, 0);
#pragma unroll
            for (int i = 0; i < 4; ++i) {
                unsigned short gh = (i & 1) ? (unsigned short)(g1p[t][nb * 2 + (i >> 1)] >> 16)
                                            : (unsigned short)(g1p[t][nb * 2 + (i >> 1)]);
                hd_s[t][(q * 4 + i) * 136 + c] = f2b(acc[i] * b2f(gh));
            }
        }
    }

    // preload all 16 GEMM4 B-frags before the fence
    short8 dw[16];
#pragma unroll
    for (int h = 0; h < 16; ++h)
        dw[h] = *(const short8*)(wd + ((h >> 2) * 16 + l15) * TWOD + (h & 3) * 32 + q * 8);

    lds_fence();   // da1 visible

    // ---- GEMM4: dx = da1 @ W1  (32x128x64) -> out[:, :64] ----
    short8 dfa[2][4];
#pragma unroll
    for (int t = 0; t < 2; ++t)
#pragma unroll
        for (int kb = 0; kb < 4; ++kb)
            dfa[t][kb] = *(const short8*)(&hd_s[t][l15 * 136 + kb * 32 + q * 8]);
#pragma unroll
    for (int t = 0; t < 2; ++t)
#pragma unroll
        for (int nb = 0; nb < 4; ++nb) {
            float4v acc = {0.f, 0.f, 0.f, 0.f};
#pragma unroll
            for (int kb = 0; kb < 4; ++kb)
                acc = __builtin_amdgcn_mfma_f32_16x16x32_bf16(dfa[t][kb], dw[nb * 4 + kb], acc, 0, 0, 0);
#pragma unroll
            for (int i = 0; i < 4; ++i)
                out[(row0 + t * 16 + q * 4 + i) * TWOD + nb * 16 + l15] = acc[i];
        }
}

extern "C" void kernel_launch(void* const* d_in, const int* in_sizes, int n_in,
                              void* d_out, int out_size, void* d_ws, size_t ws_size,
                              hipStream_t stream) {
    const float* inp = (const float*)d_in[1];
    const float* W1  = (const float*)d_in[2];
    const float* b1  = (const float*)d_in[3];
    const float* W2  = (const float*)d_in[4];
    const float* b2  = (const float*)d_in[5];

    unsigned short* wa = (unsigned short*)d_ws;
    unsigned short* wd = wa + 8192;
    unsigned short* wb = wd + 8192;
    unsigned short* wc = wb + 32768;

    prep_weights<<<128, 256, 0, stream>>>(W1, W2, wa, wd, wb, wc);

    const int rows = in_sizes[1] / TWOD;
    geognn_kernel<<<rows / 32, 64, 0, stream>>>(inp, b1, b2, wa, wd, wb, wc,
                                                (float*)d_out);
}

// Round 4
// 345.822 us; speedup vs baseline: 1.4104x; 1.0445x over previous
//
#include <hip/hip_runtime.h>

#define DD    64      // D
#define TWOD  128     // 2*D
#define RD    256     // RANK*D
#define NT    3       // 16-row subtiles per wave (48 rows)

typedef __attribute__((ext_vector_type(8))) short short8;   // 8 bf16 (MFMA A/B frag)
typedef __attribute__((ext_vector_type(4))) float float4v;  // MFMA C/D frag
typedef __attribute__((ext_vector_type(4))) unsigned uint4v;
typedef unsigned long long ull;
typedef unsigned short ush;

__device__ __forceinline__ ush f2b(float f) {
    unsigned u = __builtin_bit_cast(unsigned, f);
    u += 0x7fffu + ((u >> 16) & 1u);
    return (ush)(u >> 16);
}
__device__ __forceinline__ float b2f(ush s) {
    unsigned u = ((unsigned)s) << 16;
    return __builtin_bit_cast(float, u);
}
// packed f32->bf16 RNE: one VALU op for two converts (identical rounding to f2b)
__device__ __forceinline__ unsigned cvt_pk_bf16(float lo, float hi) {
    unsigned r;
    asm("v_cvt_pk_bf16_f32 %0, %1, %2" : "=v"(r) : "v"(lo), "v"(hi));
    return r;
}
// two bf16 stores at unrelated addresses from one packed convert (2 VALU vs 8)
__device__ __forceinline__ void store_pair(ush* p0, ush* p1, float lo, float hi) {
    unsigned pk = cvt_pk_bf16(lo, hi);
    *p0 = (ush)pk;
    *p1 = (ush)(pk >> 16);
}
// tanh via 1 - 2*rcp(1+exp2(k*x)): 3 VALU + 2 trans (exp, rcp)
__device__ __forceinline__ float ftanh(float x) {
    float e, r;
    asm("v_exp_f32 %0, %1" : "=v"(e) : "v"(x * 2.885390082f));   // exp2(2*log2e*x)
    asm("v_rcp_f32 %0, %1" : "=v"(r) : "v"(e + 1.0f));
    return __builtin_fmaf(-2.0f, r, 1.0f);
}
// Single-wave workgroup: DS ops execute in order per wave, so lgkmcnt(0) +
// a compiler memory fence replaces __syncthreads() (no vmcnt(0) drain ->
// global prefetches stay in flight across stage boundaries).
__device__ __forceinline__ void lds_fence() {
    asm volatile("s_waitcnt lgkmcnt(0)" ::: "memory");
}

// ---------------------------------------------------------------------------
// Prep: bf16 weight layouts so MFMA B-frags are contiguous 16B reads.
// ---------------------------------------------------------------------------
__global__ void prep_weights(const float* __restrict__ W1, const float* __restrict__ W2,
                             ush* __restrict__ wa, ush* __restrict__ wd,
                             ush* __restrict__ wb, ush* __restrict__ wc) {
    int t = blockIdx.x * blockDim.x + threadIdx.x;
    if (t < 8192) {
        wa[t] = f2b(W1[t]);
        int c = t >> 7, r = t & 127;
        wd[t] = f2b(W1[r * 64 + c]);
    }
    if (t < 32768) {
        wb[t] = f2b(W2[t]);
        int c = t >> 8, k = t & 255;
        wc[t] = f2b(W2[k * 128 + c]);
    }
}

// ---------------------------------------------------------------------------
// One wave per 48-row tile (three 16-row subtiles), PHASE-MAJOR: each weight
// fragment batch is loaded once and consumed by all three subtiles (weight
// VMEM per row x0.67 vs R3). LDS 32640 B -> 5 blocks/CU (same occupancy as
// R3's measured ~5 waves/CU). v_s demoted to bf16 to fit the 32768 budget.
// Tail: grid = ceil(rows/48); last block clamps row0 (idempotent re-writes).
// ---------------------------------------------------------------------------
__global__ __launch_bounds__(64, 2) void geognn_kernel(
    const float* __restrict__ inp, const float* __restrict__ b1, const float* __restrict__ b2,
    const ush* __restrict__ wa, const ush* __restrict__ wd,
    const ush* __restrict__ wb, const ush* __restrict__ wc,
    float* __restrict__ out, long nrows) {

    // per subtile: phase A (GEMM1->2, 3->4) stride 136 (4352 B);
    //              phase B (GEMM2->mid->3)  stride 264 (8448 B). Time-aliased.
    __shared__ __align__(16) ush hd_s[NT][16 * 264];   // 25344 B
    __shared__ ush v_s[NT][16][68];                    // 6528 B (bf16)
    __shared__ float4v y_s[NT][16];                    // 768 B

    const int  l   = threadIdx.x;
    const int  l15 = l & 15;
    const int  q   = l >> 4;
    long row0 = (long)blockIdx.x * (16 * NT);
    if (row0 + 16 * NT > nrows) row0 = nrows - 16 * NT;   // tail overlap (idempotent)

    // ---- V tiles -> LDS as bf16 (pair-converted) ----
#pragma unroll
    for (int t = 0; t < NT; ++t)
#pragma unroll
        for (int r = 0; r < 16; r += 2) {
            float v0 = inp[(row0 + t * 16 + r)     * TWOD + DD + l];
            float v1 = inp[(row0 + t * 16 + r + 1) * TWOD + DD + l];
            store_pair(&v_s[t][r][l], &v_s[t][r + 1][l], v0, v1);
        }

    // ---- x A-frags, all subtiles: A[m=l15][k=kb*32+q*8+j] ----
    short8 ax[NT][2];
#pragma unroll
    for (int t = 0; t < NT; ++t)
#pragma unroll
        for (int kb = 0; kb < 2; ++kb) {
            const float4v* p = (const float4v*)(inp + (row0 + t * 16 + l15) * TWOD + kb * 32 + q * 8);
            float4v f0 = p[0], f1 = p[1];
            uint4v pk = { cvt_pk_bf16(f0.x, f0.y), cvt_pk_bf16(f0.z, f0.w),
                          cvt_pk_bf16(f1.x, f1.y), cvt_pk_bf16(f1.z, f1.w) };
            ax[t][kb] = __builtin_bit_cast(short8, pk);
        }

    // biases (lane's C-columns: n = nb*16 + l15)
    float b1v[8];
#pragma unroll
    for (int nb = 0; nb < 8; ++nb) b1v[nb] = b1[nb * 16 + l15];
    float b2v[16];
#pragma unroll
    for (int nb = 0; nb < 16; ++nb) b2v[nb] = b2[nb * 16 + l15];

    // ---- GEMM1: h = tanh(x @ W1^T + b1)  (48x64x128); 16 B-frags, used 3x ----
    short8 aw[16];
#pragma unroll
    for (int h = 0; h < 16; ++h)
        aw[h] = *(const short8*)(wa + ((h >> 1) * 16 + l15) * DD + (h & 1) * 32 + q * 8);

    unsigned g1p[NT][16];   // packed bf16 (1-h^2), pairs over i
#pragma unroll
    for (int nb = 0; nb < 8; ++nb) {
        const int c = nb * 16 + l15;
#pragma unroll
        for (int t = 0; t < NT; ++t) {
            float4v acc = {0.f, 0.f, 0.f, 0.f};
            acc = __builtin_amdgcn_mfma_f32_16x16x32_bf16(ax[t][0], aw[nb * 2 + 0], acc, 0, 0, 0);
            acc = __builtin_amdgcn_mfma_f32_16x16x32_bf16(ax[t][1], aw[nb * 2 + 1], acc, 0, 0, 0);
#pragma unroll
            for (int i = 0; i < 4; i += 2) {
                float h0 = ftanh(acc[i]     + b1v[nb]);
                float h1 = ftanh(acc[i + 1] + b1v[nb]);
                store_pair(&hd_s[t][(q * 4 + i) * 136 + c],
                           &hd_s[t][(q * 4 + i + 1) * 136 + c], h0, h1);
                g1p[t][nb * 2 + (i >> 1)] = cvt_pk_bf16(1.f - h0 * h0, 1.f - h1 * h1);
            }
        }
    }

    // preload GEMM2 pair-0 B-frags BEFORE the fence (stays in flight across it)
    short8 bwA[8], bwB[8];
#pragma unroll
    for (int h = 0; h < 8; ++h)
        bwA[h] = *(const short8*)(wb + ((h >> 2) * 16 + l15) * TWOD + (h & 3) * 32 + q * 8);

    lds_fence();   // h writes, v_s visible wave-wide

    // ---- GEMM2: u = tanh(h @ W2^T + b2)  (48x128x256), fused y partials ----
    short8 ha[NT][4];
#pragma unroll
    for (int t = 0; t < NT; ++t)
#pragma unroll
        for (int kb = 0; kb < 4; ++kb)
            ha[t][kb] = *(const short8*)(&hd_s[t][l15 * 136 + kb * 32 + q * 8]);

    lds_fence();   // drain ha reads: h alias dies, d alias writes may begin

    float yp[NT][4] = {};
#pragma unroll
    for (int p = 0; p < 8; ++p) {
        short8* cur = (p & 1) ? bwB : bwA;
        short8* nxt = (p & 1) ? bwA : bwB;
        if (p < 7) {
#pragma unroll
            for (int h = 0; h < 8; ++h)
                nxt[h] = *(const short8*)(wb + (((p + 1) * 2 + (h >> 2)) * 16 + l15) * TWOD
                                          + (h & 3) * 32 + q * 8);
        }
#pragma unroll
        for (int s = 0; s < 2; ++s) {
            const int nb = p * 2 + s;
            const int n  = nb * 16 + l15;
            const int c4 = nb * 4 + (l15 >> 2);
#pragma unroll
            for (int t = 0; t < NT; ++t) {
                float4v acc = {0.f, 0.f, 0.f, 0.f};
#pragma unroll
                for (int kb = 0; kb < 4; ++kb)
                    acc = __builtin_amdgcn_mfma_f32_16x16x32_bf16(ha[t][kb], cur[s * 4 + kb], acc, 0, 0, 0);
                float u0 = ftanh(acc[0] + b2v[nb]);
                float u1 = ftanh(acc[1] + b2v[nb]);
                float u2 = ftanh(acc[2] + b2v[nb]);
                float u3 = ftanh(acc[3] + b2v[nb]);
                store_pair(&hd_s[t][(q * 4 + 0) * 264 + n], &hd_s[t][(q * 4 + 1) * 264 + n], u0, u1);
                store_pair(&hd_s[t][(q * 4 + 2) * 264 + n], &hd_s[t][(q * 4 + 3) * 264 + n], u2, u3);
                yp[t][0] += b2f(v_s[t][q * 4 + 0][c4]) * u0;
                yp[t][1] += b2f(v_s[t][q * 4 + 1][c4]) * u1;
                yp[t][2] += b2f(v_s[t][q * 4 + 2][c4]) * u2;
                yp[t][3] += b2f(v_s[t][q * 4 + 3][c4]) * u3;
            }
        }
    }

    // complete y (each j=l15&3 summed over the 4 lanes sharing it within the quad-row group)
#pragma unroll
    for (int t = 0; t < NT; ++t)
#pragma unroll
        for (int i = 0; i < 4; ++i) {
            yp[t][i] += __shfl_xor(yp[t][i], 4, 64);
            yp[t][i] += __shfl_xor(yp[t][i], 8, 64);
        }
    if (l15 < 4) {
#pragma unroll
        for (int t = 0; t < NT; ++t)
#pragma unroll
            for (int i = 0; i < 4; ++i)
                ((float*)&y_s[t][q * 4 + i])[l15] = yp[t][i];
    }

    // preload GEMM3 nb=0 B-frags before the fence
    short8 cwA[8], cwB[8];
#pragma unroll
    for (int kb = 0; kb < 8; ++kb)
        cwA[kb] = *(const short8*)(wc + l15 * RD + kb * 32 + q * 8);

    lds_fence();   // u (d alias), y_s visible

    // ---- fused mid-pass: per row, lane l owns cells n=4l..4l+3 of u ----
    //   dv_l = 2*sum_j y_j*u[4l+j]  -> out (coalesced)
    //   da2[4l+j] = 2*y_j*v_l*(1-u^2) -> write back in place (same lane, same addr)
#pragma unroll
    for (int t = 0; t < NT; ++t)
#pragma unroll
        for (int r = 0; r < 16; ++r) {
            ull uu = *(const ull*)(&hd_s[t][r * 264 + 4 * l]);
            float4v y = y_s[t][r];
            float vv = b2f(v_s[t][r][l]);
            float u0 = b2f((ush)uu);
            float u1 = b2f((ush)(uu >> 16));
            float u2 = b2f((ush)(uu >> 32));
            float u3 = b2f((ush)(uu >> 48));
            float dvv = y.x * u0 + y.y * u1 + y.z * u2 + y.w * u3;
            out[(row0 + t * 16 + r) * TWOD + DD + l] = -2.0f * dvv;
            float t0 = 2.0f * y.x * vv * (1.0f - u0 * u0);
            float t1 = 2.0f * y.y * vv * (1.0f - u1 * u1);
            float t2 = 2.0f * y.z * vv * (1.0f - u2 * u2);
            float t3 = 2.0f * y.w * vv * (1.0f - u3 * u3);
            unsigned w0 = cvt_pk_bf16(t0, t1);
            unsigned w1 = cvt_pk_bf16(t2, t3);
            ull w = (ull)w0 | ((ull)w1 << 32);
            *(ull*)(&hd_s[t][r * 264 + 4 * l]) = w;
        }

    lds_fence();   // da2 visible

    // ---- GEMM3: dh = da2 @ W2  (48x256x128); da1 = dh*(1-h^2) -> h alias ----
    short8 da[NT][8];
#pragma unroll
    for (int t = 0; t < NT; ++t)
#pragma unroll
        for (int kb = 0; kb < 8; ++kb)
            da[t][kb] = *(const short8*)(&hd_s[t][l15 * 264 + kb * 32 + q * 8]);

    lds_fence();   // drain da reads: d alias dies, h alias (da1) writes may begin

#pragma unroll
    for (int nb = 0; nb < 8; ++nb) {
        short8* cur = (nb & 1) ? cwB : cwA;
        short8* nxt = (nb & 1) ? cwA : cwB;
        if (nb < 7) {
#pragma unroll
            for (int kb = 0; kb < 8; ++kb)
                nxt[kb] = *(const short8*)(wc + ((nb + 1) * 16 + l15) * RD + kb * 32 + q * 8);
        }
        const int c = nb * 16 + l15;
#pragma unroll
        for (int t = 0; t < NT; ++t) {
            float4v acc = {0.f, 0.f, 0.f, 0.f};
#pragma unroll
            for (int kb = 0; kb < 8; ++kb)
                acc = __builtin_amdgcn_mfma_f32_16x16x32_bf16(da[t][kb], cur[kb], acc, 0, 0, 0);
            unsigned glo = g1p[t][nb * 2 + 0], ghi = g1p[t][nb * 2 + 1];
            float d0 = acc[0] * b2f((ush)glo);
            float d1 = acc[1] * b2f((ush)(glo >> 16));
            float d2 = acc[2] * b2f((ush)ghi);
            float d3 = acc[3] * b2f((ush)(ghi >> 16));
            store_pair(&hd_s[t][(q * 4 + 0) * 136 + c], &hd_s[t][(q * 4 + 1) * 136 + c], d0, d1);
            store_pair(&hd_s[t][(q * 4 + 2) * 136 + c], &hd_s[t][(q * 4 + 3) * 136 + c], d2, d3);
        }
    }

    // preload all 16 GEMM4 B-frags before the fence
    short8 dw[16];
#pragma unroll
    for (int h = 0; h < 16; ++h)
        dw[h] = *(const short8*)(wd + ((h >> 2) * 16 + l15) * TWOD + (h & 3) * 32 + q * 8);

    lds_fence();   // da1 visible

    // ---- GEMM4: dx = da1 @ W1  (48x128x64) -> out[:, :64] ----
    short8 dfa[NT][4];
#pragma unroll
    for (int t = 0; t < NT; ++t)
#pragma unroll
        for (int kb = 0; kb < 4; ++kb)
            dfa[t][kb] = *(const short8*)(&hd_s[t][l15 * 136 + kb * 32 + q * 8]);
#pragma unroll
    for (int t = 0; t < NT; ++t)
#pragma unroll
        for (int nb = 0; nb < 4; ++nb) {
            float4v acc = {0.f, 0.f, 0.f, 0.f};
#pragma unroll
            for (int kb = 0; kb < 4; ++kb)
                acc = __builtin_amdgcn_mfma_f32_16x16x32_bf16(dfa[t][kb], dw[nb * 4 + kb], acc, 0, 0, 0);
#pragma unroll
            for (int i = 0; i < 4; ++i)
                out[(row0 + t * 16 + q * 4 + i) * TWOD + nb * 16 + l15] = acc[i];
        }
}

extern "C" void kernel_launch(void* const* d_in, const int* in_sizes, int n_in,
                              void* d_out, int out_size, void* d_ws, size_t ws_size,
                              hipStream_t stream) {
    const float* inp = (const float*)d_in[1];
    const float* W1  = (const float*)d_in[2];
    const float* b1  = (const float*)d_in[3];
    const float* W2  = (const float*)d_in[4];
    const float* b2  = (const float*)d_in[5];

    ush* wa = (ush*)d_ws;
    ush* wd = wa + 8192;
    ush* wb = wd + 8192;
    ush* wc = wb + 32768;

    prep_weights<<<128, 256, 0, stream>>>(W1, W2, wa, wd, wb, wc);

    const long rows = in_sizes[1] / TWOD;
    const int  grid = (int)((rows + 16 * NT - 1) / (16 * NT));
    geognn_kernel<<<grid, 64, 0, stream>>>(inp, b1, b2, wa, wd, wb, wc,
                                           (float*)d_out, rows);
}